// Round 5
// baseline (29.967 us; speedup 1.0000x reference)
//
#include <hip/hip_runtime.h>

// JaggedAppend: out = concat_i( values[seg_i] ++ suffix_mat[i] )
// One block per segment, block=128 (2 waves). R5: 4-deep manual unroll so
// each thread holds 4 independent float4 loads in flight before storing
// (latency/ILP fix — steady-state HBM was only 3.8 TB/s, not BW-bound).
// int32 indexing (all offsets < 2^31). Plain stores (nt was neutral/worse).
// Alignment: new_start - prev_old = seg*1024B, so src/dst share phase mod
// 16B; one shared scalar head aligns both.

#define SUF 256
#define NTHR 128

typedef float floatx4 __attribute__((ext_vector_type(4)));

__global__ __launch_bounds__(NTHR) void
jagged_append_kernel(const float* __restrict__ values,
                     const int* __restrict__ prefix_sum,
                     const float* __restrict__ suffix,
                     float* __restrict__ out,
                     int B) {
    const int seg = blockIdx.x;
    if (seg >= B) return;
    const int tid = threadIdx.x;

    const int prev_old = (seg > 0) ? prefix_sum[seg - 1] : 0;
    const int end_old  = prefix_sum[seg];
    const int seg_len  = end_old - prev_old;
    const int new_start = prev_old + seg * SUF;

    const float* __restrict__ src = values + prev_old;
    float* __restrict__ dst = out + new_start;

    // Scalar head to reach 16B alignment (same phase on src and dst).
    int head = (4 - (new_start & 3)) & 3;
    if (head > seg_len) head = seg_len;
    if (tid < head) dst[tid] = src[tid];

    // Aligned float4 interior, 4-deep ILP.
    const int nvec = (seg_len - head) >> 2;
    const floatx4* __restrict__ vsrc = (const floatx4*)(src + head);
    floatx4* __restrict__ vdst = (floatx4*)(dst + head);

    int v = tid;
    for (; v + 3 * NTHR < nvec; v += 4 * NTHR) {
        floatx4 a0 = vsrc[v];
        floatx4 a1 = vsrc[v + NTHR];
        floatx4 a2 = vsrc[v + 2 * NTHR];
        floatx4 a3 = vsrc[v + 3 * NTHR];
        vdst[v]            = a0;
        vdst[v + NTHR]     = a1;
        vdst[v + 2 * NTHR] = a2;
        vdst[v + 3 * NTHR] = a3;
    }
    for (; v < nvec; v += NTHR) {
        vdst[v] = vsrc[v];
    }

    // Scalar tail (<=3 elems).
    for (int i = head + (nvec << 2) + tid; i < seg_len; i += NTHR) {
        dst[i] = src[i];
    }

    // Suffix row: 256 floats (2 scalar iters/thread); contiguous -> coalesced.
    const float* __restrict__ sfx = suffix + seg * SUF;
    float* __restrict__ sdst = dst + seg_len;
    for (int i = tid; i < SUF; i += NTHR) {
        sdst[i] = sfx[i];
    }
}

extern "C" void kernel_launch(void* const* d_in, const int* in_sizes, int n_in,
                              void* d_out, int out_size, void* d_ws, size_t ws_size,
                              hipStream_t stream) {
    const float* values     = (const float*)d_in[0];
    const int*   prefix_sum = (const int*)d_in[1];
    const float* suffix     = (const float*)d_in[2];
    float* out = (float*)d_out;

    const int B = in_sizes[1];  // 8192 segments

    jagged_append_kernel<<<B, NTHR, 0, stream>>>(values, prefix_sum, suffix, out, B);
}